// Round 1
// baseline (922.634 us; speedup 1.0000x reference)
//
#include <hip/hip_runtime.h>
#include <math.h>

#define XCH 112
#define GCH 56
#define BS  8
#define HH  128
#define WW  128
#define CHS (BS*HH*WW)      /* 131072: channel stride in [b][c][B][H][W] */
#define HW  (HH*WW)         /* 16384 */
#define DD  14

// ---------------------------------------------------------------------------
// Kernel 1: grouped 3x3x3 conv producing q (from x), k,v (from last).
// Natural layout output: qws/kws/vws[b][go][d][y][x], go in [0,56).
// Block: 256 threads = 2 rows x 128 cols. Grid: (64 y-blocks, 56 groups, 2 b).
// ---------------------------------------------------------------------------
__global__ __launch_bounds__(256) void conv_qkv_kernel(
    const float* __restrict__ x, const float* __restrict__ last,
    const float* __restrict__ Wq, const float* __restrict__ Wk,
    const float* __restrict__ Wv,
    float* __restrict__ qws, float* __restrict__ kws, float* __restrict__ vws)
{
    __shared__ float wq[54], wk[54], wv[54];
    const int tid = threadIdx.x;
    const int go = blockIdx.y;
    const int b  = blockIdx.z;
    if (tid < 54)        wq[tid]      = Wq[go*54 + tid];
    else if (tid < 108)  wk[tid-54]   = Wk[go*54 + (tid-54)];
    else if (tid < 162)  wv[tid-108]  = Wv[go*54 + (tid-108)];
    __syncthreads();

    const int xx = tid & 127;
    const int y  = blockIdx.x*2 + (tid >> 7);

    float accq[8], acck[8], accv[8];
    #pragma unroll
    for (int d = 0; d < 8; ++d) { accq[d] = 0.f; acck[d] = 0.f; accv[d] = 0.f; }

    #pragma unroll
    for (int ci = 0; ci < 2; ++ci) {
        const float* bx = x    + (size_t)(b*XCH + go*2 + ci)*CHS;
        const float* bl = last + (size_t)(b*XCH + go*2 + ci)*CHS;
        #pragma unroll
        for (int ky = 0; ky < 3; ++ky) {
            const int yy = y + ky - 1;
            const bool yok = ((unsigned)yy < (unsigned)HH);
            #pragma unroll
            for (int kx = 0; kx < 3; ++kx) {
                const int xx2 = xx + kx - 1;
                const bool ok = yok && ((unsigned)xx2 < (unsigned)WW);
                const int off = yy*WW + xx2;
                float cx[8], cl[8];
                #pragma unroll
                for (int z = 0; z < 8; ++z) {
                    cx[z] = ok ? bx[z*HW + off] : 0.f;
                    cl[z] = ok ? bl[z*HW + off] : 0.f;
                }
                #pragma unroll
                for (int kd = 0; kd < 3; ++kd) {
                    const int wi = ci*27 + kd*9 + ky*3 + kx;
                    const float wqv = wq[wi];
                    const float wkv = wk[wi];
                    const float wvv = wv[wi];
                    #pragma unroll
                    for (int d = 0; d < 8; ++d) {
                        const int z = d + kd - 1;
                        if (z >= 0 && z < 8) {
                            accq[d] = fmaf(cx[z], wqv, accq[d]);
                            acck[d] = fmaf(cl[z], wkv, acck[d]);
                            accv[d] = fmaf(cl[z], wvv, accv[d]);
                        }
                    }
                }
            }
        }
    }
    const size_t obase = (size_t)(b*GCH + go)*CHS + (size_t)y*WW + xx;
    #pragma unroll
    for (int d = 0; d < 8; ++d) {
        qws[obase + (size_t)d*HW] = accq[d];
        kws[obase + (size_t)d*HW] = acck[d];
        vws[obase + (size_t)d*HW] = accv[d];
    }
}

// ---------------------------------------------------------------------------
// Kernel 2: windowed attention + theta MLP + mask + output 1x1x1 conv (fused).
// One block per (window bp, head). 4 waves; wave handles B-slices {w, w+4}.
// Lane = token (iy*8+ix). sim row kept in 64 registers per lane.
// ---------------------------------------------------------------------------
__global__ __launch_bounds__(256) void attn_kernel(
    const float* __restrict__ qws, const float* __restrict__ kws,
    const float* __restrict__ vws,
    const float* __restrict__ pcq_w, const float* __restrict__ pcq_b,
    const float* __restrict__ pck_w, const float* __restrict__ pck_b,
    const float* __restrict__ mlp1_w, const float* __restrict__ mlp2_w1,
    const float* __restrict__ mlp2_w2, const float* __restrict__ Wout,
    float* __restrict__ out)
{
    __shared__ __align__(16) float kv[4][2][64][16]; // per-wave k/v tiles
    __shared__ float w1T[64*65];                     // mlp2_w1 transposed, pad 65
    __shared__ float t1s[4][64];
    __shared__ float m2w2[64];
    __shared__ float woutS[112];
    __shared__ float pcqS[14], pckS[14];

    const int tid = threadIdx.x;
    for (int idx = tid; idx < 4096; idx += 256) {
        const int o = idx >> 6, i = idx & 63;
        w1T[i*65 + o] = mlp2_w1[idx];
    }
    if (tid < 64)  m2w2[tid]  = mlp2_w2[tid];
    if (tid < 112) woutS[tid] = Wout[tid];
    if (tid < 14)  { pcqS[tid] = pcq_w[tid]; pckS[tid] = pck_w[tid]; }
    __syncthreads();

    const float bq = pcq_b[0];
    const float bk = pck_b[0];

    const int head = blockIdx.x & 3;
    const int bp   = blockIdx.x >> 2;
    const int wx   = bp & 15;
    const int wy   = (bp >> 4) & 15;
    const int b    = bp >> 8;

    const int wave = tid >> 6;
    const int lane = tid & 63;
    const int iy = lane >> 3, ix = lane & 7;
    const int y = wy*8 + iy, x = wx*8 + ix;

    float (*kl)[16] = kv[wave][0];
    float (*vl)[16] = kv[wave][1];

    for (int d_ = wave; d_ < 8; d_ += 4) {
        const size_t spat = (size_t)d_*HW + (size_t)y*WW + x;
        const size_t cb = (size_t)(b*GCH + head*DD)*CHS + spat;

        float qr[14], kr[14], vr[14];
        #pragma unroll
        for (int dd = 0; dd < 14; ++dd) {
            qr[dd] = qws[cb + (size_t)dd*CHS];
            kr[dd] = kws[cb + (size_t)dd*CHS];
            vr[dd] = vws[cb + (size_t)dd*CHS];
        }
        float Sq = bq, Sk = bk, diag = 0.f;
        #pragma unroll
        for (int dd = 0; dd < 14; ++dd) {
            Sq   = fmaf(qr[dd], pcqS[dd], Sq);
            Sk   = fmaf(kr[dd], pckS[dd], Sk);
            diag = fmaf(qr[dd], kr[dd], diag);
        }
        const float m1own = mlp1_w[lane];

        float4* krow = (float4*)&kl[lane][0];
        krow[0] = make_float4(kr[0], kr[1], kr[2],  kr[3]);
        krow[1] = make_float4(kr[4], kr[5], kr[6],  kr[7]);
        krow[2] = make_float4(kr[8], kr[9], kr[10], kr[11]);
        krow[3] = make_float4(kr[12], kr[13], Sk,   m1own);
        float4* vrow = (float4*)&vl[lane][0];
        vrow[0] = make_float4(vr[0], vr[1], vr[2],  vr[3]);
        vrow[1] = make_float4(vr[4], vr[5], vr[6],  vr[7]);
        vrow[2] = make_float4(vr[8], vr[9], vr[10], vr[11]);
        vrow[3] = make_float4(vr[12], vr[13], 0.f,  0.f);

        // Pass A: sim row, running max, t1 = sum_j sim*m1 (diag removed after)
        float sims[64];
        float rmax = -1e30f;
        float t1 = 0.f;
        #pragma unroll
        for (int j = 0; j < 64; ++j) {
            const float* kp = &kl[j][0];
            const float4 a0 = *(const float4*)(kp);
            const float4 a1 = *(const float4*)(kp + 4);
            const float4 a2 = *(const float4*)(kp + 8);
            const float4 a3 = *(const float4*)(kp + 12);
            float s = qr[0]*a0.x;
            s = fmaf(qr[1],  a0.y, s); s = fmaf(qr[2],  a0.z, s);
            s = fmaf(qr[3],  a0.w, s); s = fmaf(qr[4],  a1.x, s);
            s = fmaf(qr[5],  a1.y, s); s = fmaf(qr[6],  a1.z, s);
            s = fmaf(qr[7],  a1.w, s); s = fmaf(qr[8],  a2.x, s);
            s = fmaf(qr[9],  a2.y, s); s = fmaf(qr[10], a2.z, s);
            s = fmaf(qr[11], a2.w, s); s = fmaf(qr[12], a3.x, s);
            s = fmaf(qr[13], a3.y, s);
            t1 = fmaf(s, a3.w, t1);            // a3.w = mlp1_w[j]
            const float sv = s * Sq * a3.z;    // a3.z = Sk[j]
            sims[j] = sv;
            rmax = fmaxf(rmax, sv);
        }
        t1 = fmaf(-diag, m1own, t1);           // remove diagonal term

        // theta MLP
        t1s[wave][lane] = t1;
        float t2 = 0.f;
        #pragma unroll
        for (int i = 0; i < 64; ++i)
            t2 = fmaf(t1s[wave][i], w1T[i*65 + lane], t2);
        t2 = (t2 > 0.f) ? t2 : 0.1f*t2;        // leaky_relu 0.1
        float th = t2 * m2w2[lane];
        #pragma unroll
        for (int m = 32; m >= 1; m >>= 1)
            th += __shfl_xor(th, m, 64);       // all lanes: theta

        // Pass B: softmax (denominator over ALL j), hard mask, PV
        float denom = 0.f;
        float acc[14];
        #pragma unroll
        for (int dd = 0; dd < 14; ++dd) acc[dd] = 0.f;
        #pragma unroll
        for (int j = 0; j < 64; ++j) {
            const float sv = sims[j];
            const float e = __expf(sv - rmax);
            denom += e;
            const float a = (sv > th) ? e : 0.f;
            const float* vp = &vl[j][0];
            const float4 b0 = *(const float4*)(vp);
            const float4 b1 = *(const float4*)(vp + 4);
            const float4 b2 = *(const float4*)(vp + 8);
            const float4 b3 = *(const float4*)(vp + 12);
            acc[0]  = fmaf(a, b0.x, acc[0]);  acc[1]  = fmaf(a, b0.y, acc[1]);
            acc[2]  = fmaf(a, b0.z, acc[2]);  acc[3]  = fmaf(a, b0.w, acc[3]);
            acc[4]  = fmaf(a, b1.x, acc[4]);  acc[5]  = fmaf(a, b1.y, acc[5]);
            acc[6]  = fmaf(a, b1.z, acc[6]);  acc[7]  = fmaf(a, b1.w, acc[7]);
            acc[8]  = fmaf(a, b2.x, acc[8]);  acc[9]  = fmaf(a, b2.y, acc[9]);
            acc[10] = fmaf(a, b2.z, acc[10]); acc[11] = fmaf(a, b2.w, acc[11]);
            acc[12] = fmaf(a, b3.x, acc[12]); acc[13] = fmaf(a, b3.y, acc[13]);
        }
        const float inv = 1.0f / denom;

        // epilogue: fused 1x1x1 grouped conv (each in-ch -> 2 out-ch scales)
        #pragma unroll
        for (int dd = 0; dd < 14; ++dd) {
            const float val = acc[dd] * inv;
            const int c = head*DD + dd;                 // 0..55
            const size_t o0 = (size_t)(b*XCH + 2*c)*CHS + spat;
            out[o0]       = val * woutS[2*c];
            out[o0 + CHS] = val * woutS[2*c + 1];
        }
    }
}

// ---------------------------------------------------------------------------
extern "C" void kernel_launch(void* const* d_in, const int* in_sizes, int n_in,
                              void* d_out, int out_size, void* d_ws, size_t ws_size,
                              hipStream_t stream) {
    const float* x       = (const float*)d_in[0];
    const float* last    = (const float*)d_in[1];
    const float* Wq      = (const float*)d_in[2];
    const float* Wk      = (const float*)d_in[3];
    const float* Wv      = (const float*)d_in[4];
    const float* Wout    = (const float*)d_in[5];
    const float* pcq_w   = (const float*)d_in[6];
    const float* pcq_b   = (const float*)d_in[7];
    const float* pck_w   = (const float*)d_in[8];
    const float* pck_b   = (const float*)d_in[9];
    const float* mlp1_w  = (const float*)d_in[10];
    const float* mlp2_w1 = (const float*)d_in[11];
    const float* mlp2_w2 = (const float*)d_in[12];
    float* out = (float*)d_out;

    const size_t tsz = (size_t)2*GCH*CHS;   // 14,680,064 floats per tensor
    float* qws = (float*)d_ws;
    float* kws = qws + tsz;
    float* vws = kws + tsz;

    conv_qkv_kernel<<<dim3(64, 56, 2), 256, 0, stream>>>(
        x, last, Wq, Wk, Wv, qws, kws, vws);
    attn_kernel<<<dim3(512*4), 256, 0, stream>>>(
        qws, kws, vws, pcq_w, pcq_b, pck_w, pck_b,
        mlp1_w, mlp2_w1, mlp2_w2, Wout, out);
}